// Round 1
// baseline (1533.104 us; speedup 1.0000x reference)
//
#include <hip/hip_runtime.h>
#include <hip/hip_bf16.h>
#include <math.h>

// Problem constants (match reference)
#define B_   16
#define T_   1024
#define D_   512
#define V_   5000
#define L_   128
#define S_   257          // 2L+1 extended states
#define J_   129          // blank + L label slots
#define M_   (B_*T_)      // 16384 rows of the projection
#define NT_  40           // ceil(V/128) N-tiles for partial LSE
#define NEGF (-1e30f)

// ---------------------------------------------------------------------------
// Kernel 1: C = hs@W + b, fused per-row partial logsumexp per 128-col tile.
// 128x128 block tile, 256 threads, 8x8 micro-tile, K-chunk 16. fp32 SIMT.
// Never materializes logits to global: writes (max, sumexp) partials only.
// ---------------------------------------------------------------------------
__global__ __launch_bounds__(256) void k_gemm_lse(
    const float* __restrict__ A,    // (M, 512) hs_pad flattened
    const float* __restrict__ W,    // (512, 5000)
    const float* __restrict__ bias, // (5000)
    float* __restrict__ part_m,     // (M, NT_)
    float* __restrict__ part_s)     // (M, NT_)
{
    __shared__ float As[16][128];   // [k][m] transposed for broadcast reads
    __shared__ float Bs[16][128];   // [k][n]
    const int bx = blockIdx.x;      // row tile (128 of them)
    const int by = blockIdx.y;      // col tile (40)
    const int tid = threadIdx.x;
    const int tx = tid & 15, ty = tid >> 4;
    const int rowBase = bx * 128, colBase = by * 128;

    float acc[8][8];
#pragma unroll
    for (int i = 0; i < 8; i++)
#pragma unroll
        for (int j = 0; j < 8; j++) acc[i][j] = 0.f;

    for (int k0 = 0; k0 < D_; k0 += 16) {
        // A tile: 128 rows x 16 k = 512 float4, 2 per thread
#pragma unroll
        for (int l = 0; l < 2; l++) {
            int f = tid + l * 256;
            int r = f >> 2, q = f & 3;
            float4 a4 = *(const float4*)&A[(size_t)(rowBase + r) * D_ + k0 + q * 4];
            As[q * 4 + 0][r] = a4.x; As[q * 4 + 1][r] = a4.y;
            As[q * 4 + 2][r] = a4.z; As[q * 4 + 3][r] = a4.w;
        }
        // B tile: 16 k x 128 cols = 512 float4, 2 per thread (guard col < V)
#pragma unroll
        for (int l = 0; l < 2; l++) {
            int f = tid + l * 256;
            int kk = f >> 5, cq = f & 31;
            int col = colBase + cq * 4;
            float4 b4 = make_float4(0.f, 0.f, 0.f, 0.f);
            if (col < V_) b4 = *(const float4*)&W[(size_t)(k0 + kk) * V_ + col];
            *(float4*)&Bs[kk][cq * 4] = b4;
        }
        __syncthreads();
#pragma unroll
        for (int kk = 0; kk < 16; kk++) {
            float aR[8], bR[8];
#pragma unroll
            for (int i = 0; i < 8; i++) aR[i] = As[kk][ty * 8 + i];
#pragma unroll
            for (int j = 0; j < 8; j++) bR[j] = Bs[kk][tx * 8 + j];
#pragma unroll
            for (int i = 0; i < 8; i++)
#pragma unroll
                for (int j = 0; j < 8; j++)
                    acc[i][j] = fmaf(aR[i], bR[j], acc[i][j]);
        }
        __syncthreads();
    }

    // bias add + per-row (max, sum exp) partial over this 128-col tile.
    // Row r = rowBase + ty*8 + i is owned by the 16 threads sharing ty
    // (consecutive lanes) -> width-16 shuffle reduction.
#pragma unroll
    for (int i = 0; i < 8; i++) {
        float m = -INFINITY;
#pragma unroll
        for (int j = 0; j < 8; j++) {
            int col = colBase + tx * 8 + j;
            if (col < V_) { acc[i][j] += bias[col]; m = fmaxf(m, acc[i][j]); }
        }
#pragma unroll
        for (int off = 1; off < 16; off <<= 1) m = fmaxf(m, __shfl_xor(m, off, 16));
        float s = 0.f;
#pragma unroll
        for (int j = 0; j < 8; j++) {
            int col = colBase + tx * 8 + j;
            if (col < V_) s += __expf(acc[i][j] - m);
        }
#pragma unroll
        for (int off = 1; off < 16; off <<= 1) s += __shfl_xor(s, off, 16);
        if (tx == 0) {
            int row = rowBase + ty * 8 + i;
            part_m[(size_t)row * NT_ + by] = m;
            part_s[(size_t)row * NT_ + by] = s;
        }
    }
}

// ---------------------------------------------------------------------------
// Kernel 2: combine LSE partials -> lse[row]
// ---------------------------------------------------------------------------
__global__ void k_lse_reduce(const float* __restrict__ part_m,
                             const float* __restrict__ part_s,
                             float* __restrict__ lse)
{
    int row = blockIdx.x * 256 + threadIdx.x;
    if (row >= M_) return;
    float m = -INFINITY;
    for (int i = 0; i < NT_; i++) m = fmaxf(m, part_m[(size_t)row * NT_ + i]);
    float s = 0.f;
    for (int i = 0; i < NT_; i++)
        s += part_s[(size_t)row * NT_ + i] * __expf(part_m[(size_t)row * NT_ + i] - m);
    lse[row] = m + __logf(s);
}

// ---------------------------------------------------------------------------
// Kernel 3: gather needed W columns (blank + per-batch labels) transposed to
// row-major Wg[b][j][d] so the dot kernel reads contiguously. Also bias.
// ---------------------------------------------------------------------------
__global__ void k_gather_w(const float* __restrict__ W,
                           const float* __restrict__ bias,
                           const int* __restrict__ ys,
                           float* __restrict__ Wg,     // (B, J, 512)
                           float* __restrict__ bg)     // (B, J)
{
    int b = blockIdx.x, j = blockIdx.y;
    int lab = (j == 0) ? 0 : ys[b * L_ + (j - 1)];
    float* dst = &Wg[((size_t)b * J_ + j) * D_];
    for (int d = threadIdx.x; d < D_; d += blockDim.x)
        dst[d] = W[(size_t)d * V_ + lab];
    if (threadIdx.x == 0) bg[b * J_ + j] = bias[lab];
}

// ---------------------------------------------------------------------------
// Kernel 4: label logits ll[b][t][j] = dot(hs[b,t,:], Wg[b,j,:]) + bg[b,j]
// 16 t's staged in LDS (pad 516 to break bank aliasing); lane mapping puts
// same j on 16 consecutive lanes -> Wg reads broadcast from cache.
// ---------------------------------------------------------------------------
#define HPAD 516
__global__ __launch_bounds__(256) void k_label_logits(
    const float* __restrict__ hs,
    const float* __restrict__ Wg,
    const float* __restrict__ bg,
    float* __restrict__ ll)        // (B, T, J)
{
    __shared__ float hs_s[16 * HPAD];
    int b = blockIdx.x, tBase = blockIdx.y * 16;
    int tid = threadIdx.x;
    // load 16 x 512 floats = 2048 float4, 8 per thread
#pragma unroll
    for (int l = 0; l < 8; l++) {
        int f = tid + l * 256;
        int t = f >> 7, q = f & 127;
        float4 h4 = *(const float4*)&hs[((size_t)(b * T_) + tBase + t) * D_ + q * 4];
        *(float4*)&hs_s[t * HPAD + q * 4] = h4;
    }
    __syncthreads();
    for (int base = 0; base < 16 * J_; base += 256) {
        int idx = base + tid;
        if (idx < 16 * J_) {
            int t = idx & 15, j = idx >> 4;
            const float* w = &Wg[((size_t)b * J_ + j) * D_];
            const float* h = &hs_s[t * HPAD];
            float acc = 0.f;
            for (int d = 0; d < D_; d += 4) {
                float4 w4 = *(const float4*)&w[d];
                float4 h4 = *(const float4*)&h[d];
                acc = fmaf(w4.x, h4.x, acc); acc = fmaf(w4.y, h4.y, acc);
                acc = fmaf(w4.z, h4.z, acc); acc = fmaf(w4.w, h4.w, acc);
            }
            ll[((size_t)(b * T_) + tBase + t) * J_ + j] = acc + bg[b * J_ + j];
        }
    }
}

// ---------------------------------------------------------------------------
// Kernel 5: CTC alpha recursion. One block per batch. 257 states in LDS
// double buffer, one barrier per time step, stop at hlens[b] (== reference
// freeze semantics). Writes per-batch loss.
// ---------------------------------------------------------------------------
__global__ __launch_bounds__(320) void k_ctc_alpha(
    const float* __restrict__ ll,      // (B, T, J)
    const float* __restrict__ lse,     // (B*T)
    const int* __restrict__ hlens,
    const int* __restrict__ ys,
    const int* __restrict__ ys_lens,
    float* __restrict__ loss_b)        // (B)
{
    __shared__ float al[2][S_];
    int b = blockIdx.x;
    int s = threadIdx.x;
    int hl = hlens[b];
    bool act = (s < S_);
    int j = 0;
    bool use3 = false;
    if (act && (s & 1)) {
        j = (s + 1) >> 1;                       // label slot (1-based into J)
        if (s >= 3) {
            int lab   = ys[b * L_ + ((s - 1) >> 1)];
            int labm2 = ys[b * L_ + ((s - 3) >> 1)];
            use3 = (lab != labm2);
        }
        // s == 1: skip path reads padded alpha[-1] = NEG in the reference
    }
    const float* llb  = ll  + (size_t)b * T_ * J_;
    const float* lseb = lse + (size_t)b * T_;

    if (act) {
        float v = NEGF;
        if (s == 0) v = llb[0] - lseb[0];
        else if (s == 1) v = llb[1] - lseb[0];
        al[0][s] = v;
    }
    __syncthreads();

    for (int t = 1; t < hl; t++) {
        int cur = (t - 1) & 1, nxt = t & 1;
        if (act) {
            float a1 = al[cur][s];
            float a2 = (s >= 1) ? al[cur][s - 1] : NEGF;
            float a3 = use3     ? al[cur][s - 2] : NEGF;
            float m = fmaxf(fmaxf(a1, a2), fmaxf(a3, NEGF));
            float v = m + __logf(__expf(a1 - m) + __expf(a2 - m) + __expf(a3 - m));
            float lp = llb[(size_t)t * J_ + j] - lseb[t];
            al[nxt][s] = v + lp;
        }
        __syncthreads();
    }

    if (threadIdx.x == 0) {
        int yl = ys_lens[b];
        int f = (hl - 1) & 1;
        int i1 = 2 * yl;
        int i2 = (i1 > 0) ? i1 - 1 : 0;
        float a = al[f][i1], c = al[f][i2];
        float m = fmaxf(a, c);
        float llv = m + __logf(__expf(a - m) + __expf(c - m));
        float loss = -llv;
        if (!isfinite(loss) || loss >= 1e29f) loss = 0.f;
        loss_b[b] = loss;
    }
}

// ---------------------------------------------------------------------------
// Kernel 6: final scalar: sum(loss_b) / sum(ys_lens). d_out is poisoned per
// call so this must write every launch.
// ---------------------------------------------------------------------------
__global__ void k_final(const float* __restrict__ loss_b,
                        const int* __restrict__ ys_lens,
                        float* __restrict__ out)
{
    int t = threadIdx.x;
    float v = (t < B_) ? loss_b[t] : 0.f;
    int   n = (t < B_) ? ys_lens[t] : 0;
    for (int off = 32; off > 0; off >>= 1) {
        v += __shfl_down(v, off, 64);
        n += __shfl_down(n, off, 64);
    }
    if (t == 0) out[0] = v / (float)n;
}

// ---------------------------------------------------------------------------
extern "C" void kernel_launch(void* const* d_in, const int* in_sizes, int n_in,
                              void* d_out, int out_size, void* d_ws, size_t ws_size,
                              hipStream_t stream)
{
    const float* hs      = (const float*)d_in[0];  // (B,T,D)
    const int*   hlens   = (const int*)  d_in[1];  // (B)
    const int*   ys      = (const int*)  d_in[2];  // (B,L)
    const int*   ys_lens = (const int*)  d_in[3];  // (B)
    const float* W       = (const float*)d_in[4];  // (D,V)
    const float* bias    = (const float*)d_in[5];  // (V)
    float* out = (float*)d_out;

    // Workspace layout (floats). Total ~18 MB.
    float* ws = (float*)d_ws;
    float* part_m = ws;                               // M*NT   = 655360
    float* part_s = part_m + (size_t)M_ * NT_;        // 655360
    float* lse    = part_s + (size_t)M_ * NT_;        // 16384
    float* Wg     = lse    + M_;                      // B*J*D  = 1056768
    float* bg     = Wg     + (size_t)B_ * J_ * D_;    // B*J    = 2064
    float* llab   = bg     + (size_t)B_ * J_;         // B*T*J  = 2113536
    float* loss_b = llab   + (size_t)B_ * T_ * J_;    // 16

    // 1) projection + fused partial LSE (the 84-GFLOP bulk)
    k_gemm_lse<<<dim3(M_ / 128, NT_), 256, 0, stream>>>(hs, W, bias, part_m, part_s);
    // 2) gather label columns of W (independent of 1)
    k_gather_w<<<dim3(B_, J_), 128, 0, stream>>>(W, bias, ys, Wg, bg);
    // 3) label logits
    k_label_logits<<<dim3(B_, T_ / 16), 256, 0, stream>>>(hs, Wg, bg, llab);
    // 4) combine LSE partials
    k_lse_reduce<<<M_ / 256, 256, 0, stream>>>(part_m, part_s, lse);
    // 5) CTC forward recursion
    k_ctc_alpha<<<B_, 320, 0, stream>>>(llab, lse, hlens, ys, ys_lens, loss_b);
    // 6) final scalar
    k_final<<<1, 64, 0, stream>>>(loss_b, ys_lens, out);
}

// Round 2
// 694.962 us; speedup vs baseline: 2.2060x; 2.2060x over previous
//
#include <hip/hip_runtime.h>
#include <hip/hip_bf16.h>
#include <math.h>

// Problem constants (match reference)
#define B_   16
#define T_   1024
#define D_   512
#define V_   5000
#define VP_  5120         // V padded to 128
#define L_   128
#define S_   257          // 2L+1 extended states
#define J_   129          // blank + L label slots
#define M_   (B_*T_)      // 16384 rows of the projection
#define NT_  40           // ceil(V/128) N-tiles for partial LSE
#define NEGF (-1e30f)

typedef __attribute__((ext_vector_type(8))) short short8;
typedef __attribute__((ext_vector_type(4))) float float4v;

__device__ inline void load_lds_16(const void* g, void* l) {
    __builtin_amdgcn_global_load_lds(
        (const __attribute__((address_space(1))) unsigned int*)g,
        (__attribute__((address_space(3))) unsigned int*)l, 16, 0, 0);
}

__device__ inline unsigned short f2bf(float f) {
    union { float f; unsigned int u; } x; x.f = f;
    // RNE round to bf16
    unsigned int r = x.u + 0x7FFFu + ((x.u >> 16) & 1u);
    return (unsigned short)(r >> 16);
}

// ---------------------------------------------------------------------------
// Kernel 0a: hs fp32 -> bf16 row-major (M, 512)
// ---------------------------------------------------------------------------
__global__ __launch_bounds__(256) void k_convert_hs(
    const float* __restrict__ hs, unsigned short* __restrict__ Ah)
{
    size_t base = ((size_t)blockIdx.x * 256 + threadIdx.x) * 8;
    float4 a = *(const float4*)&hs[base];
    float4 b = *(const float4*)&hs[base + 4];
    short8 o;
    o[0] = (short)f2bf(a.x); o[1] = (short)f2bf(a.y);
    o[2] = (short)f2bf(a.z); o[3] = (short)f2bf(a.w);
    o[4] = (short)f2bf(b.x); o[5] = (short)f2bf(b.y);
    o[6] = (short)f2bf(b.z); o[7] = (short)f2bf(b.w);
    *(short8*)&Ah[base] = o;
}

// ---------------------------------------------------------------------------
// Kernel 0b: W (512, 5000) fp32 -> Wt (5120, 512) bf16 transposed, pad zero
// ---------------------------------------------------------------------------
__global__ __launch_bounds__(256) void k_transpose_w(
    const float* __restrict__ W, unsigned short* __restrict__ Wt)
{
    __shared__ float tile[32][33];
    int v0 = blockIdx.x * 32, k0 = blockIdx.y * 32;
    int tx = threadIdx.x, ty = threadIdx.y;  // (32, 8)
#pragma unroll
    for (int r = 0; r < 4; r++) {
        int kk = r * 8 + ty;
        float val = 0.f;
        if (v0 + tx < V_) val = W[(size_t)(k0 + kk) * V_ + v0 + tx];
        tile[kk][tx] = val;
    }
    __syncthreads();
#pragma unroll
    for (int r = 0; r < 4; r++) {
        int vloc = r * 8 + ty;
        Wt[(size_t)(v0 + vloc) * D_ + k0 + tx] = f2bf(tile[tx][vloc]);
    }
}

// ---------------------------------------------------------------------------
// Kernel 1: C = hs@W + b with fused per-row partial logsumexp per 128-col
// tile. bf16 MFMA 16x16x32, 128x128 block tile, 4 waves (2x2), 4x4 frags,
// global_load_lds width-16 staging. Writes (max, sumexp) partials only.
// ---------------------------------------------------------------------------
__global__ __launch_bounds__(256) void k_gemm_lse_mfma(
    const unsigned short* __restrict__ Ah,   // (M, 512) bf16
    const unsigned short* __restrict__ Wt,   // (5120, 512) bf16 = W^T
    const float* __restrict__ bias,          // (5000)
    float* __restrict__ part_m,              // (M, NT_)
    float* __restrict__ part_s)              // (M, NT_)
{
    __shared__ unsigned short As[128 * 32];  // [m][k] k-contiguous
    __shared__ unsigned short Bs[128 * 32];  // [n][k]
    __shared__ float sm_m[2][128];
    __shared__ float sm_s[2][128];

    const int bx = blockIdx.x;          // row tile (128)
    const int by = blockIdx.y;          // col tile (40)
    const int tid = threadIdx.x;
    const int rowBase = bx * 128, colBase = by * 128;
    const int lane = tid & 63, wv = tid >> 6;
    const int wi = wv >> 1, wj = wv & 1;    // 2x2 wave grid
    const int g = lane >> 4, lo = lane & 15;

    float4v acc[4][4];
#pragma unroll
    for (int i = 0; i < 4; i++)
#pragma unroll
        for (int j = 0; j < 4; j++) acc[i][j] = (float4v){0.f, 0.f, 0.f, 0.f};

    for (int it = 0; it < 16; it++) {
        const int k0 = it * 32;
        __syncthreads();
        // stage A: 128 rows x 32 bf16 = 8192 B; 512 slots of 16 B, 2/thread
#pragma unroll
        for (int l = 0; l < 2; l++) {
            int slot = tid + l * 256;
            int r = slot >> 2, q = slot & 3;
            load_lds_16(&Ah[(size_t)(rowBase + r) * D_ + k0 + q * 8],
                        &As[r * 32 + q * 8]);
            load_lds_16(&Wt[(size_t)(colBase + r) * D_ + k0 + q * 8],
                        &Bs[r * 32 + q * 8]);
        }
        __syncthreads();

        short8 a[4], b[4];
#pragma unroll
        for (int i = 0; i < 4; i++)
            a[i] = *(const short8*)&As[(wi * 64 + i * 16 + lo) * 32 + g * 8];
#pragma unroll
        for (int j = 0; j < 4; j++)
            b[j] = *(const short8*)&Bs[(wj * 64 + j * 16 + lo) * 32 + g * 8];
#pragma unroll
        for (int i = 0; i < 4; i++)
#pragma unroll
            for (int j = 0; j < 4; j++)
                acc[i][j] = __builtin_amdgcn_mfma_f32_16x16x32_bf16(
                    a[i], b[j], acc[i][j], 0, 0, 0);
    }

    // Epilogue: per-row max / sumexp over this wave's 64 cols, then combine
    // the two wj waves in LDS. D-frag mapping: col = lane&15, row=(lane>>4)*4+reg.
    float bj[4]; bool vj[4];
#pragma unroll
    for (int j = 0; j < 4; j++) {
        int col = colBase + wj * 64 + j * 16 + lo;
        vj[j] = (col < V_);
        bj[j] = vj[j] ? bias[col] : 0.f;
    }
#pragma unroll
    for (int i = 0; i < 4; i++) {
#pragma unroll
        for (int r = 0; r < 4; r++) {
            float m = -INFINITY;
#pragma unroll
            for (int j = 0; j < 4; j++)
                if (vj[j]) m = fmaxf(m, acc[i][j][r] + bj[j]);
#pragma unroll
            for (int off = 1; off < 16; off <<= 1)
                m = fmaxf(m, __shfl_xor(m, off, 16));
            float s = 0.f;
#pragma unroll
            for (int j = 0; j < 4; j++)
                if (vj[j]) s += __expf(acc[i][j][r] + bj[j] - m);
#pragma unroll
            for (int off = 1; off < 16; off <<= 1)
                s += __shfl_xor(s, off, 16);
            if (lo == 0) {
                int rowl = wi * 64 + i * 16 + g * 4 + r;
                sm_m[wj][rowl] = m;
                sm_s[wj][rowl] = s;
            }
        }
    }
    __syncthreads();
    if (tid < 128) {
        float m0 = sm_m[0][tid], m1 = sm_m[1][tid];
        float m = fmaxf(m0, m1);
        float s = 0.f;
        if (m > -INFINITY) {
            s = sm_s[0][tid] * __expf(m0 - m) + sm_s[1][tid] * __expf(m1 - m);
        }
        part_m[(size_t)(rowBase + tid) * NT_ + by] = m;
        part_s[(size_t)(rowBase + tid) * NT_ + by] = s;
    }
}

// ---------------------------------------------------------------------------
// Kernel 2: combine LSE partials -> lse[row]
// ---------------------------------------------------------------------------
__global__ void k_lse_reduce(const float* __restrict__ part_m,
                             const float* __restrict__ part_s,
                             float* __restrict__ lse)
{
    int row = blockIdx.x * 256 + threadIdx.x;
    if (row >= M_) return;
    float m = -INFINITY;
    for (int i = 0; i < NT_; i++) m = fmaxf(m, part_m[(size_t)row * NT_ + i]);
    float s = 0.f;
    for (int i = 0; i < NT_; i++)
        s += part_s[(size_t)row * NT_ + i] * __expf(part_m[(size_t)row * NT_ + i] - m);
    lse[row] = m + __logf(s);
}

// ---------------------------------------------------------------------------
// Kernel 3: gather needed W columns (blank + per-batch labels) transposed to
// row-major Wg[b][j][d] so the dot kernel reads contiguously. Also bias.
// ---------------------------------------------------------------------------
__global__ void k_gather_w(const float* __restrict__ W,
                           const float* __restrict__ bias,
                           const int* __restrict__ ys,
                           float* __restrict__ Wg,     // (B, J, 512)
                           float* __restrict__ bg)     // (B, J)
{
    int b = blockIdx.x, j = blockIdx.y;
    int lab = (j == 0) ? 0 : ys[b * L_ + (j - 1)];
    float* dst = &Wg[((size_t)b * J_ + j) * D_];
    for (int d = threadIdx.x; d < D_; d += blockDim.x)
        dst[d] = W[(size_t)d * V_ + lab];
    if (threadIdx.x == 0) bg[b * J_ + j] = bias[lab];
}

// ---------------------------------------------------------------------------
// Kernel 4: label logits ll[b][t][j] = dot(hs[b,t,:], Wg[b,j,:]) + bg[b,j]
// ---------------------------------------------------------------------------
#define HPAD 516
__global__ __launch_bounds__(256) void k_label_logits(
    const float* __restrict__ hs,
    const float* __restrict__ Wg,
    const float* __restrict__ bg,
    float* __restrict__ ll)        // (B, T, J)
{
    __shared__ float hs_s[16 * HPAD];
    int b = blockIdx.x, tBase = blockIdx.y * 16;
    int tid = threadIdx.x;
#pragma unroll
    for (int l = 0; l < 8; l++) {
        int f = tid + l * 256;
        int t = f >> 7, q = f & 127;
        float4 h4 = *(const float4*)&hs[((size_t)(b * T_) + tBase + t) * D_ + q * 4];
        *(float4*)&hs_s[t * HPAD + q * 4] = h4;
    }
    __syncthreads();
    for (int base = 0; base < 16 * J_; base += 256) {
        int idx = base + tid;
        if (idx < 16 * J_) {
            int t = idx & 15, j = idx >> 4;
            const float* w = &Wg[((size_t)b * J_ + j) * D_];
            const float* h = &hs_s[t * HPAD];
            float acc = 0.f;
            for (int d = 0; d < D_; d += 4) {
                float4 w4 = *(const float4*)&w[d];
                float4 h4 = *(const float4*)&h[d];
                acc = fmaf(w4.x, h4.x, acc); acc = fmaf(w4.y, h4.y, acc);
                acc = fmaf(w4.z, h4.z, acc); acc = fmaf(w4.w, h4.w, acc);
            }
            ll[((size_t)(b * T_) + tBase + t) * J_ + j] = acc + bg[b * J_ + j];
        }
    }
}

// ---------------------------------------------------------------------------
// Kernel 5: CTC alpha recursion. One block per batch, 257 states in LDS
// double buffer, stop at hlens[b] (== reference freeze semantics).
// ---------------------------------------------------------------------------
__global__ __launch_bounds__(320) void k_ctc_alpha(
    const float* __restrict__ ll,      // (B, T, J)
    const float* __restrict__ lse,     // (B*T)
    const int* __restrict__ hlens,
    const int* __restrict__ ys,
    const int* __restrict__ ys_lens,
    float* __restrict__ loss_b)        // (B)
{
    __shared__ float al[2][S_];
    int b = blockIdx.x;
    int s = threadIdx.x;
    int hl = hlens[b];
    bool act = (s < S_);
    int j = 0;
    bool use3 = false;
    if (act && (s & 1)) {
        j = (s + 1) >> 1;
        if (s >= 3) {
            int lab   = ys[b * L_ + ((s - 1) >> 1)];
            int labm2 = ys[b * L_ + ((s - 3) >> 1)];
            use3 = (lab != labm2);
        }
    }
    const float* llb  = ll  + (size_t)b * T_ * J_;
    const float* lseb = lse + (size_t)b * T_;

    if (act) {
        float v = NEGF;
        if (s == 0) v = llb[0] - lseb[0];
        else if (s == 1) v = llb[1] - lseb[0];
        al[0][s] = v;
    }
    __syncthreads();

    for (int t = 1; t < hl; t++) {
        int cur = (t - 1) & 1, nxt = t & 1;
        if (act) {
            float a1 = al[cur][s];
            float a2 = (s >= 1) ? al[cur][s - 1] : NEGF;
            float a3 = use3     ? al[cur][s - 2] : NEGF;
            float m = fmaxf(fmaxf(a1, a2), fmaxf(a3, NEGF));
            float v = m + __logf(__expf(a1 - m) + __expf(a2 - m) + __expf(a3 - m));
            float lp = llb[(size_t)t * J_ + j] - lseb[t];
            al[nxt][s] = v + lp;
        }
        __syncthreads();
    }

    if (threadIdx.x == 0) {
        int yl = ys_lens[b];
        int f = (hl - 1) & 1;
        int i1 = 2 * yl;
        int i2 = (i1 > 0) ? i1 - 1 : 0;
        float a = al[f][i1], c = al[f][i2];
        float m = fmaxf(a, c);
        float llv = m + __logf(__expf(a - m) + __expf(c - m));
        float loss = -llv;
        if (!isfinite(loss) || loss >= 1e29f) loss = 0.f;
        loss_b[b] = loss;
    }
}

// ---------------------------------------------------------------------------
// Kernel 6: final scalar: sum(loss_b) / sum(ys_lens)
// ---------------------------------------------------------------------------
__global__ void k_final(const float* __restrict__ loss_b,
                        const int* __restrict__ ys_lens,
                        float* __restrict__ out)
{
    int t = threadIdx.x;
    float v = (t < B_) ? loss_b[t] : 0.f;
    int   n = (t < B_) ? ys_lens[t] : 0;
    for (int off = 32; off > 0; off >>= 1) {
        v += __shfl_down(v, off, 64);
        n += __shfl_down(n, off, 64);
    }
    if (t == 0) out[0] = v / (float)n;
}

// ---------------------------------------------------------------------------
extern "C" void kernel_launch(void* const* d_in, const int* in_sizes, int n_in,
                              void* d_out, int out_size, void* d_ws, size_t ws_size,
                              hipStream_t stream)
{
    const float* hs      = (const float*)d_in[0];  // (B,T,D)
    const int*   hlens   = (const int*)  d_in[1];  // (B)
    const int*   ys      = (const int*)  d_in[2];  // (B,L)
    const int*   ys_lens = (const int*)  d_in[3];  // (B)
    const float* W       = (const float*)d_in[4];  // (D,V)
    const float* bias    = (const float*)d_in[5];  // (V)
    float* out = (float*)d_out;

    // Workspace layout (floats; all offsets 16B-aligned). Total ~40 MB.
    float* ws = (float*)d_ws;
    float* part_m = ws;                               // M*NT   = 655360
    float* part_s = part_m + (size_t)M_ * NT_;        // 655360
    float* lse    = part_s + (size_t)M_ * NT_;        // 16384
    float* Wg     = lse    + M_;                      // B*J*D  = 1056768
    float* bg     = Wg     + (size_t)B_ * J_ * D_;    // 2064
    float* llab   = bg     + (size_t)B_ * J_;         // 2113536
    float* loss_b = llab   + (size_t)B_ * T_ * J_;    // 16
    unsigned short* Ah = (unsigned short*)(loss_b + 16);   // M*D bf16 = 16.8MB
    unsigned short* Wt = Ah + (size_t)M_ * D_;             // VP*D bf16 = 5.2MB

    // 0) convert hs -> bf16; W -> bf16 transposed (N-major, padded to 5120)
    k_convert_hs<<<(M_ * D_) / (256 * 8), 256, 0, stream>>>(hs, Ah);
    k_transpose_w<<<dim3(VP_ / 32, D_ / 32), dim3(32, 8), 0, stream>>>(W, Wt);
    // 1) projection + fused partial LSE (the 84-GFLOP bulk) via bf16 MFMA
    k_gemm_lse_mfma<<<dim3(M_ / 128, NT_), 256, 0, stream>>>(Ah, Wt, bias, part_m, part_s);
    // 2) gather label columns of W
    k_gather_w<<<dim3(B_, J_), 128, 0, stream>>>(W, bias, ys, Wg, bg);
    // 3) label logits
    k_label_logits<<<dim3(B_, T_ / 16), 256, 0, stream>>>(hs, Wg, bg, llab);
    // 4) combine LSE partials
    k_lse_reduce<<<M_ / 256, 256, 0, stream>>>(part_m, part_s, lse);
    // 5) CTC forward recursion
    k_ctc_alpha<<<B_, 320, 0, stream>>>(llab, lse, hlens, ys, ys_lens, loss_b);
    // 6) final scalar
    k_final<<<1, 64, 0, stream>>>(loss_b, ys_lens, out);
}